// Round 11
// baseline (15434.779 us; speedup 1.0000x reference)
//
#include <hip/hip_runtime.h>

#define HH 512
#define OO 256
#define BB 64
#define SS 1024
#define TT 256
#define KK 1280   // H(ctx) + O(target) + H(h)

typedef __attribute__((ext_vector_type(8))) short bh8;
typedef __attribute__((ext_vector_type(8))) _Float16 hf8;
typedef __attribute__((ext_vector_type(4))) float fx4;

__device__ __forceinline__ unsigned short f2bf(float x) {
    union { float f; unsigned int u; } v; v.f = x;
    unsigned int r = v.u + 0x7fffu + ((v.u >> 16) & 1u);
    return (unsigned short)(r >> 16);
}
__device__ __forceinline__ float bf2f(unsigned short s) {
    union { unsigned int u; float f; } z; z.u = ((unsigned int)s) << 16; return z.f;
}

// Pack W_cat = [W_ih | W_hh] (j-permuted; see round-0 comment) into MFMA
// B-fragment-major bf16 hi/lo split: W = hi + lo, lo = bf16(W - f32(hi)).
__global__ void prep_weights(const float* __restrict__ W_ih,
                             const float* __restrict__ W_hh,
                             unsigned short* __restrict__ wfH,
                             unsigned short* __restrict__ wfL) {
    int g = blockIdx.x * 256 + threadIdx.x;     // 64*40*2*64 = 327680 groups
    if (g >= 64 * 40 * 2 * 64) return;
    int lane = g & 63;
    int nt = (g >> 6) & 1;
    int kk = (g >> 7) % 40;
    int ht = (g >> 7) / 40;
    int c = nt * 16 + (lane & 15);
    int gate = c >> 3, rr = c & 7;
    int j = gate * 512 + ht * 8 + rr;
    int kbase = kk * 32 + (lane >> 4) * 8;
    unsigned short* dh = wfH + (size_t)g * 8;
    unsigned short* dl = wfL + (size_t)g * 8;
#pragma unroll
    for (int r = 0; r < 8; ++r) {
        int k = kbase + r;
        float v = (k < 768) ? W_ih[(size_t)j * 768 + k]
                            : W_hh[(size_t)j * 512 + (k - 768)];
        unsigned short hi = f2bf(v);
        dh[r] = hi;
        dl[r] = f2bf(v - bf2f(hi));
    }
}

__global__ void prep_misc(const float* __restrict__ hidden,
                          const float* __restrict__ cell,
                          float* __restrict__ h, float* __restrict__ c) {
    const int total = 32768 + 32768;
    for (int i = blockIdx.x * 256 + threadIdx.x; i < total; i += gridDim.x * 256) {
        if (i < 32768) h[i] = hidden[i];
        else           c[i - 32768] = cell[i - 32768];
    }
}

// One-time fp32 -> fp16 convert of encoder_outputs (33.5M elems, 8/thread).
__global__ void prep_enc(const float* __restrict__ enc,
                         _Float16* __restrict__ ench) {
    const size_t i = ((size_t)blockIdx.x * 256 + threadIdx.x) * 8;
    const float4 a = *(const float4*)(enc + i);
    const float4 b = *(const float4*)(enc + i + 4);
    hf8 o;
    o[0] = (_Float16)a.x; o[1] = (_Float16)a.y;
    o[2] = (_Float16)a.z; o[3] = (_Float16)a.w;
    o[4] = (_Float16)b.x; o[5] = (_Float16)b.y;
    o[6] = (_Float16)b.z; o[7] = (_Float16)b.w;
    *(hf8*)(ench + i) = o;
}

// K1: blocks 0..255 = attention partial for (b, S-quarter qs): 16 waves x 16
// rows each, in-block combine of the 16 wave partials -> pm4/pl4 + fp16
// unnormalized ctx partial. Blocks 256..319 = FC producing out[t-1].
// Fence-free; visibility via kernel boundaries.
__global__ void __launch_bounds__(1024)
step_attn4(int t, const _Float16* __restrict__ ench,
           const float* __restrict__ h,
           float* __restrict__ pm4, float* __restrict__ pl4,
           _Float16* __restrict__ pctx4,
           const float* __restrict__ W_fc, const float* __restrict__ b_fc,
           float* __restrict__ out) {
    const int tid = threadIdx.x;
    const int lane = tid & 63;
    const int w = tid >> 6;          // wave 0..15

    __shared__ union {
        struct { float m[16]; float l[16]; float ctx[16][512]; } a;  // 33 KB
        struct { float acc[256][4]; } o;                             // 4 KB
    } sh;

    const int u = blockIdx.x;
    if (u < 256) {
        const int b = u >> 2, qs = u & 3;
        const float* hb = h + b * HH + lane * 8;
        const float4 h0 = *(const float4*)hb;
        const float4 h1 = *(const float4*)(hb + 4);
        float m = -3.0e38f, l = 0.f;
        float cx[8];
#pragma unroll
        for (int j = 0; j < 8; ++j) cx[j] = 0.f;
        // wave w owns rows qs*256 + w*16 .. +15, processed as 8 row-pairs
        const _Float16* er =
            ench + ((size_t)(b * SS + qs * 256 + w * 16)) * HH + lane * 8;
        for (int rp = 0; rp < 8; ++rp) {
            const hf8 ev = *(const hf8*)er;
            const hf8 fv = *(const hf8*)(er + HH);
            float e[8], f[8];
#pragma unroll
            for (int j = 0; j < 8; ++j) {
                e[j] = (float)ev[j];
                f[j] = (float)fv[j];
            }
            float dA = e[0]*h0.x + e[1]*h0.y + e[2]*h0.z + e[3]*h0.w
                     + e[4]*h1.x + e[5]*h1.y + e[6]*h1.z + e[7]*h1.w;
            float dB = f[0]*h0.x + f[1]*h0.y + f[2]*h0.z + f[3]*h0.w
                     + f[4]*h1.x + f[5]*h1.y + f[6]*h1.z + f[7]*h1.w;
#pragma unroll
            for (int off = 32; off; off >>= 1) {
                dA += __shfl_xor(dA, off);
                dB += __shfl_xor(dB, off);
            }
            const float mx = fmaxf(dA, dB);
            if (mx > m) {                      // wave-uniform branch
                const float fs = __expf(m - mx);
                l *= fs;
#pragma unroll
                for (int j = 0; j < 8; ++j) cx[j] *= fs;
                m = mx;
            }
            const float pA = __expf(dA - m);
            const float pB = __expf(dB - m);
            l += pA + pB;
#pragma unroll
            for (int j = 0; j < 8; ++j) cx[j] += pA * e[j] + pB * f[j];
            er += 2 * HH;
        }
        if (lane == 0) { sh.a.m[w] = m; sh.a.l[w] = l; }
        *(float4*)&sh.a.ctx[w][lane * 8]     = make_float4(cx[0], cx[1], cx[2], cx[3]);
        *(float4*)&sh.a.ctx[w][lane * 8 + 4] = make_float4(cx[4], cx[5], cx[6], cx[7]);
        __syncthreads();
        // in-block combine of the 16 wave partials (unnormalized output)
        float M = -3.0e38f;
#pragma unroll
        for (int q = 0; q < 16; ++q) M = fmaxf(M, sh.a.m[q]);
        float wq[16]; float lsb = 0.f;
#pragma unroll
        for (int q = 0; q < 16; ++q) {
            wq[q] = __expf(sh.a.m[q] - M);
            lsb += wq[q] * sh.a.l[q];
        }
        if (tid < 512) {
            float s = 0.f;
#pragma unroll
            for (int q = 0; q < 16; ++q) s += wq[q] * sh.a.ctx[q][tid];
            pctx4[((size_t)(b * 4 + qs)) * 512 + tid] = (_Float16)s;
        }
        if (tid == 0) { pm4[b * 4 + qs] = M; pl4[b * 4 + qs] = lsb; }
    } else if (t > 0) {
        // FC for out[t-1], b = u-256: 256 outputs x 4-way K split
        const int b = u - 256;
        const int o = tid & 255, kq = tid >> 8;
        float acc = 0.f;
        const float* hp = h + b * HH + kq * 128;
        const float* wp = W_fc + (size_t)o * HH + kq * 128;
#pragma unroll 8
        for (int k2 = 0; k2 < 128; ++k2) acc += hp[k2] * wp[k2];
        sh.o.acc[o][kq] = acc;
        __syncthreads();
        if (tid < 256) {
            float vv = sh.o.acc[tid][0] + sh.o.acc[tid][1]
                     + sh.o.acc[tid][2] + sh.o.acc[tid][3] + b_fc[tid];
            out[((size_t)b * TT + (t - 1)) * OO + tid] = vv;
        }
    }
}

// K2: gates MFMA with inline softmax-combine A-construction + cell update.
// Reads hin (old h), writes hout (other buffer) -> no cross-block race.
__global__ void __launch_bounds__(256)
step_gates4(int t, const float* __restrict__ pm4, const float* __restrict__ pl4,
            const _Float16* __restrict__ pctx4,
            const float* __restrict__ target, const float* __restrict__ hin,
            const unsigned short* __restrict__ wfH,
            const unsigned short* __restrict__ wfL,
            const float* __restrict__ b_ih, const float* __restrict__ b_hh,
            float* __restrict__ hout, float* __restrict__ c) {
    const int tid = threadIdx.x;
    const int lane = tid & 63;
    const int w = tid >> 6;
    __shared__ float g[64][32];
    __shared__ float cw[64][4];

    // per-b combine coefficients: cw[b][q] = exp(pm4-M)/sum(exp(pm4-M)*pl4)
    if (tid < 64) {
        const int b = tid;
        const float p0 = pm4[b*4+0], p1 = pm4[b*4+1];
        const float p2 = pm4[b*4+2], p3 = pm4[b*4+3];
        const float M = fmaxf(fmaxf(p0, p1), fmaxf(p2, p3));
        const float w0 = __expf(p0 - M), w1 = __expf(p1 - M);
        const float w2 = __expf(p2 - M), w3 = __expf(p3 - M);
        const float inv = 1.0f / (w0 * pl4[b*4+0] + w1 * pl4[b*4+1]
                                + w2 * pl4[b*4+2] + w3 * pl4[b*4+3]);
        cw[b][0] = w0 * inv; cw[b][1] = w1 * inv;
        cw[b][2] = w2 * inv; cw[b][3] = w3 * inv;
    }
    __syncthreads();

    const int ht = blockIdx.x;
    fx4 a0 = {0, 0, 0, 0}, a1 = {0, 0, 0, 0};
    const int bro = 16 * w + (lane & 15);
    const int kg = lane >> 4;
    const size_t wbase = (size_t)ht * 40 * 2 * 512;
    const float cw0 = cw[bro][0], cw1 = cw[bro][1];
    const float cw2 = cw[bro][2], cw3 = cw[bro][3];
    const _Float16* pc0 = pctx4 + ((size_t)(bro * 4 + 0)) * 512;
    const _Float16* pc1 = pctx4 + ((size_t)(bro * 4 + 1)) * 512;
    const _Float16* pc2 = pctx4 + ((size_t)(bro * 4 + 2)) * 512;
    const _Float16* pc3 = pctx4 + ((size_t)(bro * 4 + 3)) * 512;

#define GATES_MFMA_STEP(kkv)                                                   \
    {                                                                          \
        bh8 b0h = *(const bh8*)(wfH + wbase + ((kkv) * 2 + 0) * 512 + lane*8); \
        bh8 b1h = *(const bh8*)(wfH + wbase + ((kkv) * 2 + 1) * 512 + lane*8); \
        bh8 b0l = *(const bh8*)(wfL + wbase + ((kkv) * 2 + 0) * 512 + lane*8); \
        bh8 b1l = *(const bh8*)(wfL + wbase + ((kkv) * 2 + 1) * 512 + lane*8); \
        a0 = __builtin_amdgcn_mfma_f32_16x16x32_bf16(avh, b0h, a0, 0, 0, 0);   \
        a0 = __builtin_amdgcn_mfma_f32_16x16x32_bf16(avl, b0h, a0, 0, 0, 0);   \
        a0 = __builtin_amdgcn_mfma_f32_16x16x32_bf16(avh, b0l, a0, 0, 0, 0);   \
        a1 = __builtin_amdgcn_mfma_f32_16x16x32_bf16(avh, b1h, a1, 0, 0, 0);   \
        a1 = __builtin_amdgcn_mfma_f32_16x16x32_bf16(avl, b1h, a1, 0, 0, 0);   \
        a1 = __builtin_amdgcn_mfma_f32_16x16x32_bf16(avh, b1l, a1, 0, 0, 0);   \
    }

    // ctx region: kk 0..15, k = kk*32 + kg*8
    for (int kk = 0; kk < 16; ++kk) {
        const int k0 = kk * 32 + kg * 8;
        bh8 avh, avl;
#pragma unroll
        for (int j = 0; j < 8; ++j) {
            const float s = cw0 * (float)pc0[k0 + j] + cw1 * (float)pc1[k0 + j]
                          + cw2 * (float)pc2[k0 + j] + cw3 * (float)pc3[k0 + j];
            const unsigned short hi = f2bf(s);
            avh[j] = (short)hi;
            avl[j] = (short)f2bf(s - bf2f(hi));
        }
        GATES_MFMA_STEP(kk)
    }
    // target region: kk 16..23, o = k - 512
    {
        const float* tb = target + ((size_t)bro * TT + t) * OO + kg * 8 - 512;
        for (int kk = 16; kk < 24; ++kk) {
            const float* tp = tb + kk * 32;
            bh8 avh, avl;
#pragma unroll
            for (int j = 0; j < 8; ++j) {
                const float s = tp[j];
                const unsigned short hi = f2bf(s);
                avh[j] = (short)hi;
                avl[j] = (short)f2bf(s - bf2f(hi));
            }
            GATES_MFMA_STEP(kk)
        }
    }
    // h region: kk 24..39, hidx = k - 768
    {
        const float* hb = hin + bro * HH + kg * 8 - 768;
        for (int kk = 24; kk < 40; ++kk) {
            const float* hp = hb + kk * 32;
            bh8 avh, avl;
#pragma unroll
            for (int j = 0; j < 8; ++j) {
                const float s = hp[j];
                const unsigned short hi = f2bf(s);
                avh[j] = (short)hi;
                avl[j] = (short)f2bf(s - bf2f(hi));
            }
            GATES_MFMA_STEP(kk)
        }
    }
#undef GATES_MFMA_STEP

    const int crow = (lane >> 4) * 4;
#pragma unroll
    for (int r = 0; r < 4; ++r) {
        g[16 * w + crow + r][lane & 15]        = a0[r];
        g[16 * w + crow + r][16 + (lane & 15)] = a1[r];
    }
    __syncthreads();
#pragma unroll
    for (int p = 0; p < 2; ++p) {
        const int idx = tid * 2 + p;
        const int b = idx >> 3, r = idx & 7;
        const int hidx = ht * 8 + r;
        float gi = g[b][r]      + b_ih[hidx]        + b_hh[hidx];
        float gf = g[b][8 + r]  + b_ih[512 + hidx]  + b_hh[512 + hidx];
        float gg = g[b][16 + r] + b_ih[1024 + hidx] + b_hh[1024 + hidx];
        float go = g[b][24 + r] + b_ih[1536 + hidx] + b_hh[1536 + hidx];
        float ig = 1.f / (1.f + __expf(-gi));
        float fg = 1.f / (1.f + __expf(-gf));
        float g2 = tanhf(gg);
        float og = 1.f / (1.f + __expf(-go));
        float cn = fg * c[b * HH + hidx] + ig * g2;
        float hn = og * tanhf(cn);
        c[b * HH + hidx] = cn;
        hout[b * HH + hidx] = hn;
    }
}

// Final FC: out[TT-1] from final h.
__global__ void __launch_bounds__(1024)
fc_final(const float* __restrict__ h, const float* __restrict__ W_fc,
         const float* __restrict__ b_fc, float* __restrict__ out) {
    __shared__ float acc[256][4];
    const int tid = threadIdx.x;
    const int b = blockIdx.x;
    const int o = tid & 255, kq = tid >> 8;
    float a = 0.f;
    const float* hp = h + b * HH + kq * 128;
    const float* wp = W_fc + (size_t)o * HH + kq * 128;
#pragma unroll 8
    for (int k2 = 0; k2 < 128; ++k2) a += hp[k2] * wp[k2];
    acc[o][kq] = a;
    __syncthreads();
    if (tid < 256) {
        float vv = acc[tid][0] + acc[tid][1] + acc[tid][2] + acc[tid][3] + b_fc[tid];
        out[((size_t)b * TT + (TT - 1)) * OO + tid] = vv;
    }
}

extern "C" void kernel_launch(void* const* d_in, const int* in_sizes, int n_in,
                              void* d_out, int out_size, void* d_ws, size_t ws_size,
                              hipStream_t stream) {
    const float* enc    = (const float*)d_in[0];
    const float* hidden = (const float*)d_in[1];
    const float* cellp  = (const float*)d_in[2];
    const float* target = (const float*)d_in[3];
    const float* W_ih   = (const float*)d_in[4];
    const float* W_hh   = (const float*)d_in[5];
    const float* b_ih   = (const float*)d_in[6];
    const float* b_hh   = (const float*)d_in[7];
    const float* W_fc   = (const float*)d_in[8];
    const float* b_fc   = (const float*)d_in[9];
    float* out = (float*)d_out;

    char* base = (char*)d_ws;
    float* hA             = (float*)(base + 0);                  // 131,072 B
    float* hB             = (float*)(base + 131072);             // 131,072 B
    float* c              = (float*)(base + 262144);             // 131,072 B
    unsigned short* wfH   = (unsigned short*)(base + 393216);    // 5,242,880 B
    unsigned short* wfL   = (unsigned short*)(base + 5636096);   // 5,242,880 B
    float* pm4            = (float*)(base + 10878976);           // 1,024 B
    float* pl4            = (float*)(base + 10880000);           // 1,024 B
    _Float16* pctx4       = (_Float16*)(base + 10881024);        // 262,144 B
    _Float16* ench        = (_Float16*)(base + 11143168);        // 67,108,864 B
    // end: 78,252,032 B (R9 proved ws_size >= 80,289,792)

    prep_weights<<<dim3(1280), dim3(256), 0, stream>>>(W_ih, W_hh, wfH, wfL);
    prep_misc<<<dim3(256), dim3(256), 0, stream>>>(hidden, cellp, hA, c);
    prep_enc<<<dim3(16384), dim3(256), 0, stream>>>(enc, ench);

    for (int t = 0; t < TT; ++t) {
        float* hcur = (t & 1) ? hB : hA;
        float* hnxt = (t & 1) ? hA : hB;
        step_attn4<<<dim3(320), dim3(1024), 0, stream>>>(
            t, ench, hcur, pm4, pl4, pctx4, W_fc, b_fc, out);
        step_gates4<<<dim3(64), dim3(256), 0, stream>>>(
            t, pm4, pl4, pctx4, target, hcur, wfH, wfL, b_ih, b_hh, hnxt, c);
    }
    // t=255 wrote hnxt = hA (256 even)
    fc_final<<<dim3(64), dim3(1024), 0, stream>>>(hA, W_fc, b_fc, out);
}